// Round 1
// baseline (465.989 us; speedup 1.0000x reference)
//
#include <hip/hip_runtime.h>
#include <hip/hip_bf16.h>

typedef __attribute__((ext_vector_type(8))) short bf16x8;
typedef __attribute__((ext_vector_type(4))) float f32x4;
typedef unsigned short u16;
typedef unsigned int u32;

__device__ __forceinline__ u32 bf16_rne(float f) {
  u32 u = __float_as_uint(f);
  return (u + 0x7FFFu + ((u >> 16) & 1u)) >> 16;
}
__device__ __forceinline__ float bf16_val(u32 b) { return __uint_as_float(b << 16); }

__device__ __forceinline__ void g2l16(const u16* g, u16* l) {
  __builtin_amdgcn_global_load_lds(
      (const __attribute__((address_space(1))) u32*)g,
      (__attribute__((address_space(3))) u32*)l, 16, 0, 0);
}

// ---- split fp32 array into bf16 hi/lo (no transpose) ----
__global__ void split_arr(const float* __restrict__ in,
                          u16* __restrict__ hi, u16* __restrict__ lo, int n4) {
  int i = blockIdx.x * 256 + threadIdx.x;
  if (i >= n4) return;
  float4 v = ((const float4*)in)[i];
  u32 h0 = bf16_rne(v.x), h1 = bf16_rne(v.y), h2 = bf16_rne(v.z), h3 = bf16_rne(v.w);
  u32 l0 = bf16_rne(v.x - bf16_val(h0));
  u32 l1 = bf16_rne(v.y - bf16_val(h1));
  u32 l2 = bf16_rne(v.z - bf16_val(h2));
  u32 l3 = bf16_rne(v.w - bf16_val(h3));
  ushort4 hv; hv.x = (u16)h0; hv.y = (u16)h1; hv.z = (u16)h2; hv.w = (u16)h3;
  ushort4 lv; lv.x = (u16)l0; lv.y = (u16)l1; lv.z = (u16)l2; lv.w = (u16)l3;
  ((ushort4*)hi)[i] = hv;
  ((ushort4*)lo)[i] = lv;
}

// ---- transpose each 256x256 fp32 slice and split into bf16 hi/lo arrays ----
__global__ void split_transpose256(const float* __restrict__ in,
                                   u16* __restrict__ hi, u16* __restrict__ lo) {
  __shared__ float tile[32][33];
  const size_t off = (size_t)blockIdx.z * 65536;
  const int tx = threadIdx.x, ty = threadIdx.y;
#pragma unroll
  for (int i = 0; i < 4; ++i) {
    int y = blockIdx.y * 32 + ty + i * 8;
    int x = blockIdx.x * 32 + tx;
    tile[ty + i * 8][tx] = in[off + (size_t)y * 256 + x];
  }
  __syncthreads();
#pragma unroll
  for (int i = 0; i < 4; ++i) {
    float v = tile[tx][ty + i * 8];
    u32 hb = bf16_rne(v);
    u32 lb = bf16_rne(v - bf16_val(hb));
    size_t idx = off + (size_t)(blockIdx.x * 32 + ty + i * 8) * 256 + blockIdx.y * 32 + tx;
    hi[idx] = (u16)hb;
    lo[idx] = (u16)lb;
  }
}

// ---------------- fused priors-GEMM (split-bf16) + dynamic routing ----------------
// M = 256 rows per block = APB independent routings of R rows each.
// 1024 threads = 16 waves, wave grid mg(4) x eg(4); wave tile 64x64.
// Row r: a = r/R (wave's a: aw), b = r%R.  P[r,e]: r = mg*64 + mt*16 + q*4 + rr,
// e = eg*64 + ct*16 + li.
// GEMM: double-buffered 64KB k-slices, counted s_waitcnt vmcnt(4) + raw s_barrier.
// LDS k-granule XOR swizzle: DMA source pre-swizzled (linear LDS dest),
// readers pick slot q ^ ((li>>1)&3)  ->  2-way (free) instead of 8-way conflicts.
template <int R>
__global__ __launch_bounds__(1024, 4) void caps_route(
    const u16* __restrict__ Ahi_g,   // [64/APB blocks][256 rows][256] bf16-hi
    const u16* __restrict__ Alo_g,
    const u16* __restrict__ Whi,     // [KN][256][256] (transposed [e][d])
    const u16* __restrict__ Wlo,
    u16* __restrict__ o1hi, u16* __restrict__ o1lo,   // stage1 out (split)
    float* __restrict__ outp,                          // stage2 out
    int KN, int stage) {
  constexpr int APB = 256 / R;              // routings (a's) per block
  constexpr int ABS = (R == 128) ? 5 : 4;   // log2(a-blocks in grid)
  __shared__ u16 BUF[2][32768];             // dbuf: [Ahi|Alo|Whi|Wlo] x 16 chunks x 512 u16
  __shared__ __align__(16) float smat[4][256];
  __shared__ __align__(16) float wlog[4][256];
  __shared__ __align__(16) float probs[256];
  __shared__ float sqpart[APB][4];

  const int tid = threadIdx.x;
  const int w = tid >> 6, lane = tid & 63, q = lane >> 4, li = lane & 15;
  const int mg = w >> 2, eg = w & 3;
  const int kk = blockIdx.x >> ABS;         // weight slice (h or c)
  const int ab = blockIdx.x & ((1 << ABS) - 1);

  // ---- staging addresses: wave w stages row-block w of each of the 4 arrays ----
  const int sub = lane >> 2, p = lane & 3;
  const int gslot = p ^ ((sub >> 1) & 3);              // pre-swizzled k-granule
  const size_t goff = (size_t)w * 4096 + sub * 256 + gslot * 8;
  const u16* gAh = Ahi_g + (size_t)ab * 65536 + goff;
  const u16* gAl = Alo_g + (size_t)ab * 65536 + goff;
  const u16* gWh = Whi  + (size_t)kk * 65536 + goff;
  const u16* gWl = Wlo  + (size_t)kk * 65536 + goff;
  u16* lds0 = &BUF[0][0] + w * 512 + lane * 8;         // linear LDS dest (DMA rule)
  u16* lds1 = &BUF[1][0] + w * 512 + lane * 8;

  // ---- fragment read offset (swizzled slot) ----
  const int rslot = q ^ ((li >> 1) & 3);
  const int fbase = li * 32 + rslot * 8;               // u16 units within a chunk row-block

  f32x4 acc[4][4] = {};

  // prologue: stage k-slice 0 into buf 0 (4 DMAs per wave)
  g2l16(gAh, lds0);
  g2l16(gAl, lds0 + 8192);
  g2l16(gWh, lds0 + 16384);
  g2l16(gWl, lds0 + 24576);

  // ---- GEMM main loop: P = A (256 x 256) @ W[kk] (256 x 256), split-bf16 3-MFMA ----
#pragma unroll
  for (int ks = 0; ks < 8; ++ks) {
    const u16* B0 = (ks & 1) ? &BUF[1][0] : &BUF[0][0];
    if (ks < 7) {
      const int ko = (ks + 1) * 32;                    // next k-slice, u16 units
      u16* ln = (ks & 1) ? lds0 : lds1;
      g2l16(gAh + ko, ln);
      g2l16(gAl + ko, ln + 8192);
      g2l16(gWh + ko, ln + 16384);
      g2l16(gWl + ko, ln + 24576);
      asm volatile("s_waitcnt vmcnt(4)" ::: "memory"); // current slice landed; next 4 in flight
    } else {
      asm volatile("s_waitcnt vmcnt(0)" ::: "memory");
    }
    __builtin_amdgcn_s_barrier();
    asm volatile("" ::: "memory");
    bf16x8 bh[4], bl[4];
#pragma unroll
    for (int ct = 0; ct < 4; ++ct) {
      const u16* bp = B0 + 16384 + (eg * 4 + ct) * 512 + fbase;
      bh[ct] = *(const bf16x8*)bp;
      bl[ct] = *(const bf16x8*)(bp + 8192);
    }
#pragma unroll
    for (int mt = 0; mt < 4; ++mt) {
      const u16* ap = B0 + (mg * 4 + mt) * 512 + fbase;
      bf16x8 ah = *(const bf16x8*)ap;
      bf16x8 al = *(const bf16x8*)(ap + 8192);
#pragma unroll
      for (int ct = 0; ct < 4; ++ct) {
        acc[mt][ct] = __builtin_amdgcn_mfma_f32_16x16x32_bf16(al, bh[ct], acc[mt][ct], 0, 0, 0);
        acc[mt][ct] = __builtin_amdgcn_mfma_f32_16x16x32_bf16(ah, bl[ct], acc[mt][ct], 0, 0, 0);
        acc[mt][ct] = __builtin_amdgcn_mfma_f32_16x16x32_bf16(ah, bh[ct], acc[mt][ct], 0, 0, 0);
      }
    }
    asm volatile("" ::: "memory");
    __builtin_amdgcn_s_barrier();                      // protect buffer reuse next iter
  }

  // ---- dynamic routing (3 iterations), APB independent routings ----
  const float invR = 1.0f / R;
  const int rb = mg * 64;                              // wave's global row base
  const int aw = (R == 128) ? (mg >> 1) : mg;          // wave's a
  float v[4];
  float lg0 = 0.f, lg1 = 0.f;                          // running logits (softmax waves only)

  for (int iter = 0; iter < 3; ++iter) {
    // s[e] = sum_b probs[b] * P[b,e] : in-lane over (mt,rr), shfl over q, (R=128: LDS over mg-pair)
    float s[4];
#pragma unroll
    for (int ct = 0; ct < 4; ++ct) {
      float t = 0.f;
#pragma unroll
      for (int mt = 0; mt < 4; ++mt) {
        float4 p4;
        if (iter == 0) { p4.x = invR; p4.y = invR; p4.z = invR; p4.w = invR; }
        else           p4 = *(const float4*)&probs[rb + mt * 16 + q * 4];
        t += p4.x * acc[mt][ct][0] + p4.y * acc[mt][ct][1] +
             p4.z * acc[mt][ct][2] + p4.w * acc[mt][ct][3];
      }
      t += __shfl_xor(t, 16);
      t += __shfl_xor(t, 32);
      s[ct] = t;
    }
    if (R == 128) {
      if (q == 0) {
#pragma unroll
        for (int ct = 0; ct < 4; ++ct) smat[mg][eg * 64 + ct * 16 + li] = s[ct];
      }
      __syncthreads();
#pragma unroll
      for (int ct = 0; ct < 4; ++ct) {
        int e = eg * 64 + ct * 16 + li;
        s[ct] = smat[aw * 2][e] + smat[aw * 2 + 1][e];
      }
    }
    // squash: sq = sum_e s[e]^2 over 256 e
    float ss = s[0] * s[0] + s[1] * s[1] + s[2] * s[2] + s[3] * s[3];
    ss += __shfl_xor(ss, 1); ss += __shfl_xor(ss, 2);
    ss += __shfl_xor(ss, 4); ss += __shfl_xor(ss, 8);
    {
      bool wr = (R == 128) ? ((mg & 1) == 0) : true;
      if (wr && lane == 0) sqpart[aw][eg] = ss;
    }
    __syncthreads();
    float sq = sqpart[aw][0] + sqpart[aw][1] + sqpart[aw][2] + sqpart[aw][3];
    float scale = (sq > 0.f) ? sq / ((1.0f + sq) * sqrtf(sq)) : 0.f;
#pragma unroll
    for (int ct = 0; ct < 4; ++ct) v[ct] = s[ct] * scale;

    if (iter < 2) {
      // logits[b] += sum_e P[b,e] * v[e] : in-lane over ct, shfl over li, LDS over eg
#pragma unroll
      for (int mt = 0; mt < 4; ++mt) {
        float tt[4];
#pragma unroll
        for (int rr = 0; rr < 4; ++rr) {
          float t = acc[mt][0][rr] * v[0] + acc[mt][1][rr] * v[1] +
                    acc[mt][2][rr] * v[2] + acc[mt][3][rr] * v[3];
          t += __shfl_xor(t, 1); t += __shfl_xor(t, 2);
          t += __shfl_xor(t, 4); t += __shfl_xor(t, 8);
          tt[rr] = t;
        }
        if (li == 0)
          *(float4*)&wlog[eg][rb + mt * 16 + q * 4] =
              make_float4(tt[0], tt[1], tt[2], tt[3]);
      }
      __syncthreads();
      if (w < APB) {                 // softmax wave w <-> a = w; running logits in regs
        if (R == 128) {
          int r0 = w * 128 + lane, r1 = r0 + 64;
          lg0 += wlog[0][r0] + wlog[1][r0] + wlog[2][r0] + wlog[3][r0];
          lg1 += wlog[0][r1] + wlog[1][r1] + wlog[2][r1] + wlog[3][r1];
          float m = fmaxf(lg0, lg1);
#pragma unroll
          for (int d2 = 1; d2 < 64; d2 <<= 1) m = fmaxf(m, __shfl_xor(m, d2));
          float e0 = expf(lg0 - m), e1 = expf(lg1 - m);
          float zz = e0 + e1;
#pragma unroll
          for (int d2 = 1; d2 < 64; d2 <<= 1) zz += __shfl_xor(zz, d2);
          float inv = 1.0f / zz;
          probs[r0] = e0 * inv;
          probs[r1] = e1 * inv;
        } else {
          int r0 = w * 64 + lane;
          lg0 += wlog[0][r0] + wlog[1][r0] + wlog[2][r0] + wlog[3][r0];
          float m = lg0;
#pragma unroll
          for (int d2 = 1; d2 < 64; d2 <<= 1) m = fmaxf(m, __shfl_xor(m, d2));
          float e0 = expf(lg0 - m);
          float zz = e0;
#pragma unroll
          for (int d2 = 1; d2 < 64; d2 <<= 1) zz += __shfl_xor(zz, d2);
          probs[r0] = e0 / zz;
        }
      }
      __syncthreads();
    }
  }

  // ---- epilogue. stage1 -> split out1[a][kk][e]; stage2 -> fp32 out[kk][a][e] ----
  if (q == 0) {
    bool wr = (R == 128) ? ((mg & 1) == 0) : true;
    if (wr) {
      int ag = ab * APB + aw;        // global a
      if (stage == 1) {
        size_t ob = ((size_t)ag * KN + kk) * 256;
#pragma unroll
        for (int ct = 0; ct < 4; ++ct) {
          int e = eg * 64 + ct * 16 + li;
          u32 hb = bf16_rne(v[ct]);
          u32 lb = bf16_rne(v[ct] - bf16_val(hb));
          o1hi[ob + e] = (u16)hb;
          o1lo[ob + e] = (u16)lb;
        }
      } else {
        size_t ob = ((size_t)kk * 64 + ag) * 256;
#pragma unroll
        for (int ct = 0; ct < 4; ++ct) {
          int e = eg * 64 + ct * 16 + li;
          outp[ob + e] = v[ct];
        }
      }
    }
  }
}

extern "C" void kernel_launch(void* const* d_in, const int* in_sizes, int n_in,
                              void* d_out, int out_size, void* d_ws, size_t ws_size,
                              hipStream_t stream) {
  const float* x  = (const float*)d_in[0];   // [64][128][256]
  const float* w1 = (const float*)d_in[1];   // [64][256][256]
  const float* wc = (const float*)d_in[2];   // [32][256][256]
  float* out = (float*)d_out;                // [32][64][256]

  char* ws = (char*)d_ws;
  u16* w1hi = (u16*)(ws);                    // 8 MB
  u16* w1lo = (u16*)(ws + (8u << 20));       // 8 MB
  u16* wchi = (u16*)(ws + (16u << 20));      // 4 MB
  u16* wclo = (u16*)(ws + (20u << 20));      // 4 MB
  u16* xhi  = (u16*)(ws + (24u << 20));      // 4 MB
  u16* xlo  = (u16*)(ws + (28u << 20));      // 4 MB
  u16* o1hi = (u16*)(ws + (32u << 20));      // 2 MB
  u16* o1lo = (u16*)(ws + (34u << 20));      // 2 MB

  split_arr<<<2048, 256, 0, stream>>>(x, xhi, xlo, 524288);
  split_transpose256<<<dim3(8, 8, 64), dim3(32, 8), 0, stream>>>(w1, w1hi, w1lo);
  split_transpose256<<<dim3(8, 8, 32), dim3(32, 8), 0, stream>>>(wc, wchi, wclo);
  // stage 1: 64 kk x 32 a-pairs, M=256 (2 a's of R=128)
  caps_route<128><<<64 * 32, 1024, 0, stream>>>(xhi, xlo, w1hi, w1lo, o1hi, o1lo, nullptr, 64, 1);
  // stage 2: 32 kk x 16 a-quads, M=256 (4 a's of R=64)
  caps_route<64><<<32 * 16, 1024, 0, stream>>>(o1hi, o1lo, wchi, wclo, nullptr, nullptr, out, 32, 2);
}

// Round 2
// 360.478 us; speedup vs baseline: 1.2927x; 1.2927x over previous
//
#include <hip/hip_runtime.h>
#include <hip/hip_bf16.h>

typedef __attribute__((ext_vector_type(8))) short bf16x8;
typedef __attribute__((ext_vector_type(4))) float f32x4;
typedef unsigned short u16;
typedef unsigned int u32;

__device__ __forceinline__ u32 bf16_rne(float f) {
  u32 u = __float_as_uint(f);
  return (u + 0x7FFFu + ((u >> 16) & 1u)) >> 16;
}
__device__ __forceinline__ float bf16_val(u32 b) { return __uint_as_float(b << 16); }

__device__ __forceinline__ void g2l16(const u16* g, u16* l) {
  __builtin_amdgcn_global_load_lds(
      (const __attribute__((address_space(1))) u32*)g,
      (__attribute__((address_space(3))) u32*)l, 16, 0, 0);
}

// ---- split fp32 array into bf16 hi/lo (no transpose) ----
__global__ void split_arr(const float* __restrict__ in,
                          u16* __restrict__ hi, u16* __restrict__ lo, int n4) {
  int i = blockIdx.x * 256 + threadIdx.x;
  if (i >= n4) return;
  float4 v = ((const float4*)in)[i];
  u32 h0 = bf16_rne(v.x), h1 = bf16_rne(v.y), h2 = bf16_rne(v.z), h3 = bf16_rne(v.w);
  u32 l0 = bf16_rne(v.x - bf16_val(h0));
  u32 l1 = bf16_rne(v.y - bf16_val(h1));
  u32 l2 = bf16_rne(v.z - bf16_val(h2));
  u32 l3 = bf16_rne(v.w - bf16_val(h3));
  ushort4 hv; hv.x = (u16)h0; hv.y = (u16)h1; hv.z = (u16)h2; hv.w = (u16)h3;
  ushort4 lv; lv.x = (u16)l0; lv.y = (u16)l1; lv.z = (u16)l2; lv.w = (u16)l3;
  ((ushort4*)hi)[i] = hv;
  ((ushort4*)lo)[i] = lv;
}

// ---- transpose each 256x256 fp32 slice and split into bf16 hi/lo arrays ----
__global__ void split_transpose256(const float* __restrict__ in,
                                   u16* __restrict__ hi, u16* __restrict__ lo) {
  __shared__ float tile[32][33];
  const size_t off = (size_t)blockIdx.z * 65536;
  const int tx = threadIdx.x, ty = threadIdx.y;
#pragma unroll
  for (int i = 0; i < 4; ++i) {
    int y = blockIdx.y * 32 + ty + i * 8;
    int x = blockIdx.x * 32 + tx;
    tile[ty + i * 8][tx] = in[off + (size_t)y * 256 + x];
  }
  __syncthreads();
#pragma unroll
  for (int i = 0; i < 4; ++i) {
    float v = tile[tx][ty + i * 8];
    u32 hb = bf16_rne(v);
    u32 lb = bf16_rne(v - bf16_val(hb));
    size_t idx = off + (size_t)(blockIdx.x * 32 + ty + i * 8) * 256 + blockIdx.y * 32 + tx;
    hi[idx] = (u16)hb;
    lo[idx] = (u16)lb;
  }
}

// ---------------- fused priors-GEMM (split-bf16) + dynamic routing ----------------
// M = 256 rows per block = APB independent routings of R rows each.
// 512 threads = 8 waves, wave grid mg(2) x eg(4); per-wave tile 128 rows x 64 cols,
// acc[8][4] f32x4 = 128 unified regs; __launch_bounds__(512,2) -> 256-reg budget
// (round-1 lesson: 1024-thread blocks cap at 128 regs -> 432MB of spill traffic).
// Row r = mg*128 + mt*16 + q*4 + rr; col e = eg*64 + ct*16 + li.
// Each routing 'a' is wave-local in mg (no cross-mg s exchange needed).
// GEMM: double-buffered 64KB k-slices, counted s_waitcnt vmcnt(8) + raw s_barrier.
// LDS k-granule XOR swizzle (verified 0 bank conflicts in round 1):
// DMA source pre-swizzled (linear LDS dest), readers pick slot q ^ ((li>>1)&3).
template <int R>
__global__ __launch_bounds__(512, 2) void caps_route(
    const u16* __restrict__ Ahi_g,   // [blocks][256 rows][256] bf16-hi
    const u16* __restrict__ Alo_g,
    const u16* __restrict__ Whi,     // [KN][256][256] (transposed [e][d])
    const u16* __restrict__ Wlo,
    u16* __restrict__ o1hi, u16* __restrict__ o1lo,   // stage1 out (split)
    float* __restrict__ outp,                          // stage2 out
    int KN, int stage) {
  constexpr int APB = 256 / R;              // routings (a's) per block
  constexpr int SEG = APB / 2;              // row-segments per wave (1 or 2)
  constexpr int MTS = 8 / SEG;              // m-tiles per segment
  constexpr int ABS = (R == 128) ? 5 : 4;   // log2(a-blocks in grid)
  __shared__ u16 BUF[2][32768];             // dbuf: [Ahi|Alo|Whi|Wlo] x 16 chunks x 512 u16
  __shared__ __align__(16) float wlog[4][256];
  __shared__ __align__(16) float probs[256];
  __shared__ float sqpart[4][4];

  const int tid = threadIdx.x;
  const int w = tid >> 6, lane = tid & 63, q = lane >> 4, li = lane & 15;
  const int mg = w >> 2, eg = w & 3;        // mg 0..1, eg 0..3
  const int kk = blockIdx.x >> ABS;         // weight slice (h or c)
  const int ab = blockIdx.x & ((1 << ABS) - 1);

  // ---- staging: wave w stages row-blocks {w, w+8} of each of the 4 arrays ----
  const int sub = lane >> 2, p = lane & 3;
  const int gslot = p ^ ((sub >> 1) & 3);              // pre-swizzled k-granule
  const size_t goff = (size_t)w * 4096 + sub * 256 + gslot * 8;
  const u16* gAh = Ahi_g + (size_t)ab * 65536 + goff;
  const u16* gAl = Alo_g + (size_t)ab * 65536 + goff;
  const u16* gWh = Whi  + (size_t)kk * 65536 + goff;
  const u16* gWl = Wlo  + (size_t)kk * 65536 + goff;
  u16* l0 = &BUF[0][0] + w * 512 + lane * 8;           // linear LDS dest (DMA rule)
  u16* l1 = &BUF[1][0] + w * 512 + lane * 8;

#define STAGE8(ko, l)                          \
  do {                                         \
    g2l16(gAh + (ko), (l));                    \
    g2l16(gAh + (ko) + 32768, (l) + 4096);     \
    g2l16(gAl + (ko), (l) + 8192);             \
    g2l16(gAl + (ko) + 32768, (l) + 12288);    \
    g2l16(gWh + (ko), (l) + 16384);            \
    g2l16(gWh + (ko) + 32768, (l) + 20480);    \
    g2l16(gWl + (ko), (l) + 24576);            \
    g2l16(gWl + (ko) + 32768, (l) + 28672);    \
  } while (0)

  // ---- fragment read offset (swizzled slot) ----
  const int rslot = q ^ ((li >> 1) & 3);
  const int fbase = li * 32 + rslot * 8;               // u16 units within a chunk

  f32x4 acc[8][4] = {};

  STAGE8(0, l0);                                       // prologue: slice 0 -> buf 0

  // ---- GEMM main loop: P = A (256 x 256) @ W[kk] (256 x 256), split-bf16 3-MFMA ----
#pragma unroll
  for (int ks = 0; ks < 8; ++ks) {
    const u16* B0 = (ks & 1) ? &BUF[1][0] : &BUF[0][0];
    if (ks < 7) {
      const int ko = (ks + 1) * 32;                    // next k-slice, u16 units
      if (ks & 1) STAGE8(ko, l0); else STAGE8(ko, l1);
      asm volatile("s_waitcnt vmcnt(8)" ::: "memory"); // current 8 landed; next 8 in flight
    } else {
      asm volatile("s_waitcnt vmcnt(0)" ::: "memory");
    }
    __builtin_amdgcn_s_barrier();
    asm volatile("" ::: "memory");
    bf16x8 bh[4], bl[4];
#pragma unroll
    for (int ct = 0; ct < 4; ++ct) {
      const u16* bp = B0 + 16384 + (eg * 4 + ct) * 512 + fbase;
      bh[ct] = *(const bf16x8*)bp;
      bl[ct] = *(const bf16x8*)(bp + 8192);
    }
#pragma unroll
    for (int mt = 0; mt < 8; ++mt) {
      const u16* ap = B0 + (mg * 8 + mt) * 512 + fbase;
      bf16x8 ah = *(const bf16x8*)ap;
      bf16x8 al = *(const bf16x8*)(ap + 8192);
#pragma unroll
      for (int ct = 0; ct < 4; ++ct) {
        acc[mt][ct] = __builtin_amdgcn_mfma_f32_16x16x32_bf16(al, bh[ct], acc[mt][ct], 0, 0, 0);
        acc[mt][ct] = __builtin_amdgcn_mfma_f32_16x16x32_bf16(ah, bl[ct], acc[mt][ct], 0, 0, 0);
        acc[mt][ct] = __builtin_amdgcn_mfma_f32_16x16x32_bf16(ah, bh[ct], acc[mt][ct], 0, 0, 0);
      }
    }
    asm volatile("" ::: "memory");
    __builtin_amdgcn_s_barrier();                      // protect buffer reuse next iter
  }
#undef STAGE8

  // ---- dynamic routing (3 iterations), APB independent routings ----
  // Wave (mg,eg) owns rows mg*128..+127 = segments a = mg*SEG + sg (fully wave-local).
  const float invR = 1.0f / R;
  float v[SEG][4];
  float lg0 = 0.f, lg1 = 0.f;                          // running logits (softmax waves only)

  for (int iter = 0; iter < 3; ++iter) {
    // s[a][e] = sum_b probs[b] * P[b,e] : in-lane over (mt,rr), shfl over q
    float s[SEG][4];
#pragma unroll
    for (int sg = 0; sg < SEG; ++sg) {
#pragma unroll
      for (int ct = 0; ct < 4; ++ct) {
        float t = 0.f;
#pragma unroll
        for (int mi = 0; mi < MTS; ++mi) {
          const int mt = sg * MTS + mi;
          float4 p4;
          if (iter == 0) { p4.x = invR; p4.y = invR; p4.z = invR; p4.w = invR; }
          else           p4 = *(const float4*)&probs[mg * 128 + mt * 16 + q * 4];
          t += p4.x * acc[mt][ct][0] + p4.y * acc[mt][ct][1] +
               p4.z * acc[mt][ct][2] + p4.w * acc[mt][ct][3];
        }
        t += __shfl_xor(t, 16);
        t += __shfl_xor(t, 32);
        s[sg][ct] = t;
      }
    }
    // squash: sq_a = sum_e s_a[e]^2 over 256 e (this wave: 64 of them, LDS over eg)
#pragma unroll
    for (int sg = 0; sg < SEG; ++sg) {
      float ss = s[sg][0] * s[sg][0] + s[sg][1] * s[sg][1] +
                 s[sg][2] * s[sg][2] + s[sg][3] * s[sg][3];
      ss += __shfl_xor(ss, 1); ss += __shfl_xor(ss, 2);
      ss += __shfl_xor(ss, 4); ss += __shfl_xor(ss, 8);
      if (lane == 0) sqpart[mg * SEG + sg][eg] = ss;
    }
    __syncthreads();
#pragma unroll
    for (int sg = 0; sg < SEG; ++sg) {
      const int a = mg * SEG + sg;
      float sq = sqpart[a][0] + sqpart[a][1] + sqpart[a][2] + sqpart[a][3];
      float scale = (sq > 0.f) ? sq / ((1.0f + sq) * sqrtf(sq)) : 0.f;
#pragma unroll
      for (int ct = 0; ct < 4; ++ct) v[sg][ct] = s[sg][ct] * scale;
    }

    if (iter < 2) {
      // logits[b] += sum_e P[b,e] * v[a(b)][e] : in-lane over ct, shfl over li, LDS over eg
#pragma unroll
      for (int mt = 0; mt < 8; ++mt) {
        const int sg = mt / MTS;
        float tt[4];
#pragma unroll
        for (int rr = 0; rr < 4; ++rr) {
          float t = acc[mt][0][rr] * v[sg][0] + acc[mt][1][rr] * v[sg][1] +
                    acc[mt][2][rr] * v[sg][2] + acc[mt][3][rr] * v[sg][3];
          t += __shfl_xor(t, 1); t += __shfl_xor(t, 2);
          t += __shfl_xor(t, 4); t += __shfl_xor(t, 8);
          tt[rr] = t;
        }
        if (li == 0)
          *(float4*)&wlog[eg][mg * 128 + mt * 16 + q * 4] =
              make_float4(tt[0], tt[1], tt[2], tt[3]);
      }
      __syncthreads();
      if (w < APB) {                 // softmax wave w <-> block-local a = w
        if (R == 128) {
          int r0 = w * 128 + lane, r1 = r0 + 64;
          lg0 += wlog[0][r0] + wlog[1][r0] + wlog[2][r0] + wlog[3][r0];
          lg1 += wlog[0][r1] + wlog[1][r1] + wlog[2][r1] + wlog[3][r1];
          float m = fmaxf(lg0, lg1);
#pragma unroll
          for (int d2 = 1; d2 < 64; d2 <<= 1) m = fmaxf(m, __shfl_xor(m, d2));
          float e0 = expf(lg0 - m), e1 = expf(lg1 - m);
          float zz = e0 + e1;
#pragma unroll
          for (int d2 = 1; d2 < 64; d2 <<= 1) zz += __shfl_xor(zz, d2);
          float inv = 1.0f / zz;
          probs[r0] = e0 * inv;
          probs[r1] = e1 * inv;
        } else {
          int r0 = w * 64 + lane;
          lg0 += wlog[0][r0] + wlog[1][r0] + wlog[2][r0] + wlog[3][r0];
          float m = lg0;
#pragma unroll
          for (int d2 = 1; d2 < 64; d2 <<= 1) m = fmaxf(m, __shfl_xor(m, d2));
          float e0 = expf(lg0 - m);
          float zz = e0;
#pragma unroll
          for (int d2 = 1; d2 < 64; d2 <<= 1) zz += __shfl_xor(zz, d2);
          probs[r0] = e0 / zz;
        }
      }
      __syncthreads();
    }
  }

  // ---- epilogue. stage1 -> split out1[a][kk][e]; stage2 -> fp32 out[kk][a][e] ----
  if (q == 0) {
#pragma unroll
    for (int sg = 0; sg < SEG; ++sg) {
      const int ag = ab * APB + mg * SEG + sg;   // global a
      if (stage == 1) {
        size_t ob = ((size_t)ag * KN + kk) * 256;
#pragma unroll
        for (int ct = 0; ct < 4; ++ct) {
          int e = eg * 64 + ct * 16 + li;
          u32 hb = bf16_rne(v[sg][ct]);
          u32 lb = bf16_rne(v[sg][ct] - bf16_val(hb));
          o1hi[ob + e] = (u16)hb;
          o1lo[ob + e] = (u16)lb;
        }
      } else {
        size_t ob = ((size_t)kk * 64 + ag) * 256;
#pragma unroll
        for (int ct = 0; ct < 4; ++ct) {
          int e = eg * 64 + ct * 16 + li;
          outp[ob + e] = v[sg][ct];
        }
      }
    }
  }
}

extern "C" void kernel_launch(void* const* d_in, const int* in_sizes, int n_in,
                              void* d_out, int out_size, void* d_ws, size_t ws_size,
                              hipStream_t stream) {
  const float* x  = (const float*)d_in[0];   // [64][128][256]
  const float* w1 = (const float*)d_in[1];   // [64][256][256]
  const float* wc = (const float*)d_in[2];   // [32][256][256]
  float* out = (float*)d_out;                // [32][64][256]

  char* ws = (char*)d_ws;
  u16* w1hi = (u16*)(ws);                    // 8 MB
  u16* w1lo = (u16*)(ws + (8u << 20));       // 8 MB
  u16* wchi = (u16*)(ws + (16u << 20));      // 4 MB
  u16* wclo = (u16*)(ws + (20u << 20));      // 4 MB
  u16* xhi  = (u16*)(ws + (24u << 20));      // 4 MB
  u16* xlo  = (u16*)(ws + (28u << 20));      // 4 MB
  u16* o1hi = (u16*)(ws + (32u << 20));      // 2 MB
  u16* o1lo = (u16*)(ws + (34u << 20));      // 2 MB

  split_arr<<<2048, 256, 0, stream>>>(x, xhi, xlo, 524288);
  split_transpose256<<<dim3(8, 8, 64), dim3(32, 8), 0, stream>>>(w1, w1hi, w1lo);
  split_transpose256<<<dim3(8, 8, 32), dim3(32, 8), 0, stream>>>(wc, wchi, wclo);
  // stage 1: 64 kk x 32 a-pairs, M=256 (2 a's of R=128)
  caps_route<128><<<64 * 32, 512, 0, stream>>>(xhi, xlo, w1hi, w1lo, o1hi, o1lo, nullptr, 64, 1);
  // stage 2: 32 kk x 16 a-quads, M=256 (4 a's of R=64)
  caps_route<64><<<32 * 16, 512, 0, stream>>>(o1hi, o1lo, wchi, wclo, nullptr, nullptr, out, 32, 2);
}